// Round 8
// baseline (2579.820 us; speedup 1.0000x reference)
//
#include <hip/hip_runtime.h>

#define Hh   128
#define Ww   128
#define Cc   512
#define NHh  16
#define Kk   7
#define Ss   9
#define HW   (Hh*Ww)          // 16384
#define Mtot (8*HW)           // 131072
#define KK2  (Kk*Kk)          // 49

typedef __attribute__((ext_vector_type(8))) short bf16x8;
typedef __attribute__((ext_vector_type(4))) float f32x4;
typedef _Float16 f16;

#define AS1 __attribute__((address_space(1)))
#define AS3 __attribute__((address_space(3)))

__device__ __forceinline__ unsigned short bf16_rn(float f) {
    union { float f; unsigned u; } v; v.f = f;
    unsigned r = v.u + 0x7fffu + ((v.u >> 16) & 1u);
    return (unsigned short)(r >> 16);
}
__device__ __forceinline__ float bf16_f32(unsigned short h) {
    union { unsigned u; float f; } v; v.u = ((unsigned)h) << 16; return v.f;
}

// ----------------------------------------------------------------------------
// split f32 -> (hi, lo) bf16.  n8 = n/8  (unchanged)
// ----------------------------------------------------------------------------
__global__ __launch_bounds__(256) void split_kernel(const float* __restrict__ src,
                                                    unsigned short* __restrict__ dh,
                                                    unsigned short* __restrict__ dl,
                                                    int n8)
{
    for (int i = blockIdx.x * 256 + threadIdx.x; i < n8; i += gridDim.x * 256) {
        const float4* sp = (const float4*)src + (size_t)i * 2;
        const float4 a = sp[0], b = sp[1];
        const float vv[8] = {a.x, a.y, a.z, a.w, b.x, b.y, b.z, b.w};
        unsigned short h[8], l[8];
#pragma unroll
        for (int j = 0; j < 8; ++j) {
            h[j] = bf16_rn(vv[j]);
            l[j] = bf16_rn(vv[j] - bf16_f32(h[j]));
        }
        ushort4* dhp = (ushort4*)dh + (size_t)i * 2;
        ushort4* dlp = (ushort4*)dl + (size_t)i * 2;
        dhp[0] = make_ushort4(h[0], h[1], h[2], h[3]);
        dhp[1] = make_ushort4(h[4], h[5], h[6], h[7]);
        dlp[0] = make_ushort4(l[0], l[1], l[2], l[3]);
        dlp[1] = make_ushort4(l[4], l[5], l[6], l[7]);
    }
}

// ----------------------------------------------------------------------------
// Concat-K split GEMM (unchanged from round 6)
// ----------------------------------------------------------------------------
template<bool NT>
__global__ __launch_bounds__(256, 4) void gemm_c3(
        const unsigned short* __restrict__ Ah, const unsigned short* __restrict__ Al,
        const unsigned short* __restrict__ Wh, const unsigned short* __restrict__ Wl,
        const float* __restrict__ bias, float* __restrict__ C)
{
    __shared__ char lds[32768];             // 2 buffers x (A 8KB + B 8KB)
    const int tid  = threadIdx.x;
    const int lane = tid & 63;
    const int w    = tid >> 6;
    const int wr   = w >> 1, wc = w & 1;

    const int id = ((blockIdx.x & 7) << 9) + (blockIdx.x >> 3);
    const int m0 = (id >> 2) << 7;
    const int n0 = (id & 3) << 7;

    const size_t aRow = (size_t)(m0 + w * 16 + (lane >> 2)) * 1024 + ((lane & 3) << 4);
    const size_t bRow = (size_t)(n0 + w * 16 + (lane >> 2)) * 1024 + ((lane & 3) << 4);

    f32x4 acc[4][4];
#pragma unroll
    for (int a = 0; a < 4; ++a)
#pragma unroll
        for (int b = 0; b < 4; ++b) acc[a][b] = (f32x4)0.f;

    const int aoffL = (wr * 64 + (lane & 15)) * 64 + ((lane >> 4) << 4);
    const int boffL = 8192 + (wc * 64 + (lane & 15)) * 64 + ((lane >> 4) << 4);

#pragma unroll
    for (int q = 0; q < 2; ++q) {
        __builtin_amdgcn_global_load_lds(
            (const AS1 void*)((const char*)Ah + aRow + (size_t)q * 65536),
            (AS3 void*)(&lds[(q * 4 + w) * 1024]), 16, 0, 0);
        __builtin_amdgcn_global_load_lds(
            (const AS1 void*)((const char*)Wh + bRow + (size_t)q * 65536),
            (AS3 void*)(&lds[8192 + (q * 4 + w) * 1024]), 16, 0, 0);
    }
    __syncthreads();

    int tn = 1, kbn = 0;    // (t, kb) of the NEXT kt to stage
    for (int kt = 0; kt < 48; ++kt) {
        const int cur = kt & 1;
        if (kt < 47) {
            const char* Ap = (const char*)((tn < 2) ? Ah : Al) + (size_t)kbn * 64;
            const char* Bp = (const char*)((tn == 1) ? Wl : Wh) + (size_t)kbn * 64;
            char* dst = &lds[(cur ^ 1) * 16384];
#pragma unroll
            for (int q = 0; q < 2; ++q) {
                __builtin_amdgcn_global_load_lds(
                    (const AS1 void*)(Ap + aRow + (size_t)q * 65536),
                    (AS3 void*)(dst + (q * 4 + w) * 1024), 16, 0, 0);
                __builtin_amdgcn_global_load_lds(
                    (const AS1 void*)(Bp + bRow + (size_t)q * 65536),
                    (AS3 void*)(dst + 8192 + (q * 4 + w) * 1024), 16, 0, 0);
            }
            if (++tn == 3) { tn = 0; ++kbn; }
        }
        const char* LA = &lds[cur * 16384];
        bf16x8 a[4], b[4];
#pragma unroll
        for (int mi = 0; mi < 4; ++mi) a[mi] = *(const bf16x8*)(LA + aoffL + mi * 1024);
#pragma unroll
        for (int ni = 0; ni < 4; ++ni) b[ni] = *(const bf16x8*)(LA + boffL + ni * 1024);
#pragma unroll
        for (int mi = 0; mi < 4; ++mi)
#pragma unroll
            for (int ni = 0; ni < 4; ++ni)
                acc[mi][ni] = __builtin_amdgcn_mfma_f32_16x16x32_bf16(a[mi], b[ni], acc[mi][ni], 0, 0, 0);
        __syncthreads();
    }

    const int crow = (lane >> 4) << 2;
    const int ccol = lane & 15;
#pragma unroll
    for (int ni = 0; ni < 4; ++ni) {
        const int col = n0 + wc * 64 + ni * 16 + ccol;
        const float bv = bias[col];
#pragma unroll
        for (int mi = 0; mi < 4; ++mi) {
            float* cp = C + (size_t)(m0 + wr * 64 + mi * 16 + crow) * 512 + col;
#pragma unroll
            for (int r = 0; r < 4; ++r) {
                const float val = acc[mi][ni][r] + bv;
                if (NT) __builtin_nontemporal_store(val, cp + (size_t)r * 512);
                else    cp[(size_t)r * 512] = val;
            }
        }
    }
}

// ----------------------------------------------------------------------------
// wgt[pix][k] (unchanged)
// ----------------------------------------------------------------------------
__global__ __launch_bounds__(256) void wgt_kernel(const float* __restrict__ sims,
                                                  const int* __restrict__ sinds,
                                                  float* __restrict__ wgt)
{
    const int pix = blockIdx.x * 256 + threadIdx.x;
    const int b  = pix >> 14;
    const int ij = pix & 16383;
    const int i  = ij >> 7;
    const int j  = ij & 127;

    float os[Ss]; int oi[Ss];
    const float* sp = sims + (size_t)pix * Ss;
    const int*   ip = sinds + (size_t)pix * Ss;
#pragma unroll
    for (int s = 0; s < Ss; ++s) { os[s] = sp[s]; oi[s] = ip[s]; }

    const int si = min(max(i - 3, 0), Hh - Kk);
    const int sj = min(max(j - 3, 0), Ww - Kk);
    float* wp = wgt + (size_t)pix * KK2;

    int kidx = 0;
    for (int ki = 0; ki < Kk; ++ki) {
        const int ni = si + ki;
        for (int kj = 0; kj < Kk; ++kj, ++kidx) {
            const int nj = sj + kj;
            const int npix = (b << 14) + (ni << 7) + nj;
            const float* nsp = sims + (size_t)npix * Ss;
            const int*   nip = sinds + (size_t)npix * Ss;
            float acc = 0.f;
#pragma unroll
            for (int t = 0; t < Ss; ++t) {
                const int   nid = nip[t];
                const float nsm = nsp[t];
                float m = 0.f;
#pragma unroll
                for (int s = 0; s < Ss; ++s) m += (oi[s] == nid) ? os[s] : 0.f;
                acc += m * nsm;
            }
            wp[kidx] = acc;
        }
    }
}

// ----------------------------------------------------------------------------
// aggregation, 8-pixel row tiles, EXPLICIT register double-buffer:
// issue row ki+1's 14 global_load_dwordx4 BEFORE the 448-cyc FMA block on
// row ki (named vrA/vrB, all statically indexed). launch_bounds(128,3):
// VGPR cap ~170 fits dbuf(112)+acc(32)+addr; 6 blocks/CU like round 4
// (best FETCH), but with HBM/L2 latency hidden under FMAs.
// ----------------------------------------------------------------------------
__device__ __forceinline__ void load_row14(float4 vr[14], const float* __restrict__ rowp) {
#pragma unroll
    for (int c = 0; c < 14; ++c) vr[c] = *(const float4*)(rowp + c * Cc);
}

template<int VAR>   // 0 interior, 1 left edge (j0==0), 2 right edge (j0==120)
__device__ __forceinline__ void fma_row14(const float4 vr[14], const f16* __restrict__ cpk,
                                          f32x4 acc[8]) {
#pragma unroll
    for (int p = 0; p < 8; ++p) {
        const int d = (VAR == 0) ? 0
                    : (VAR == 1) ? -((p < 3) ? p : 3)
                                 : (3 - ((p > 4) ? (p - 4) : 0));
#pragma unroll
        for (int kj = 0; kj < 7; ++kj) {
            const float  cf = (float)cpk[p * (16 * 50) + kj];
            const float4 vv = vr[p + kj + d];
            acc[p][0] += cf * vv.x;
            acc[p][1] += cf * vv.y;
            acc[p][2] += cf * vv.z;
            acc[p][3] += cf * vv.w;
        }
    }
}

template<int VAR>
__device__ __forceinline__ void agg_rows(const float* __restrict__ vbase,
                                         const f16* __restrict__ coef,
                                         int si, int nh, f32x4 acc[8])
{
    const f16* cb = coef + nh * 50;
    const float* r0 = vbase + (size_t)si * (Ww * Cc);
    const size_t RS = (size_t)Ww * Cc;
    float4 vrA[14], vrB[14];
    load_row14(vrA, r0);
    load_row14(vrB, r0 + RS);
    fma_row14<VAR>(vrA, cb + 0 * 7, acc);
    load_row14(vrA, r0 + 2 * RS);
    fma_row14<VAR>(vrB, cb + 1 * 7, acc);
    load_row14(vrB, r0 + 3 * RS);
    fma_row14<VAR>(vrA, cb + 2 * 7, acc);
    load_row14(vrA, r0 + 4 * RS);
    fma_row14<VAR>(vrB, cb + 3 * 7, acc);
    load_row14(vrB, r0 + 5 * RS);
    fma_row14<VAR>(vrA, cb + 4 * 7, acc);
    load_row14(vrA, r0 + 6 * RS);
    fma_row14<VAR>(vrB, cb + 5 * 7, acc);
    fma_row14<VAR>(vrA, cb + 6 * 7, acc);
}

__global__ __launch_bounds__(128, 3) void agg_kernel(const float* __restrict__ v,
                                                     const float* __restrict__ attn,
                                                     const float* __restrict__ wgt,
                                                     unsigned short* __restrict__ oh,
                                                     unsigned short* __restrict__ ol)
{
    const int t   = ((blockIdx.x & 7) << 11) | (blockIdx.x >> 3);
    const int b   = t >> 11;
    const int rem = t & 2047;
    const int i   = rem >> 4;
    const int j0  = (rem & 15) << 3;
    const int tid = threadIdx.x;
    const int nh  = tid >> 3;

    __shared__ f16 coef[8 * 16 * 50];    // 12.8 KB

    const int pixbase = (b << 14) | (i << 7) | j0;
    for (int e = tid; e < 8 * 16 * KK2; e += 128) {
        const int p = e / (16 * KK2);
        const int r = e - p * (16 * KK2);
        const int h = r / KK2;
        const int k = r - h * KK2;
        const float av = attn[((size_t)(b * NHh + h) * HW + (size_t)((i << 7) | (j0 + p))) * KK2 + k];
        coef[(p * 16 + h) * 50 + k] = (f16)(av * wgt[(size_t)(pixbase + p) * KK2 + k]);
    }

    f32x4 acc[8];
#pragma unroll
    for (int p = 0; p < 8; ++p) acc[p] = (f32x4)0.f;

    const int si = min(max(i - 3, 0), Hh - Kk);
    const int cb = (j0 == 0) ? 0 : ((j0 == 120) ? (Ww - 14) : (j0 - 3));
    const float* vbase = v + ((size_t)b << 23) + ((size_t)cb << 9) + (tid << 2);

    __syncthreads();

    if (j0 == 0)            agg_rows<1>(vbase, coef, si, nh, acc);
    else if (j0 == 120)     agg_rows<2>(vbase, coef, si, nh, acc);
    else                    agg_rows<0>(vbase, coef, si, nh, acc);

#pragma unroll
    for (int p = 0; p < 8; ++p) {
        const size_t o = (size_t)(pixbase + p) * Cc + (size_t)(tid << 2);
        const unsigned short h0 = bf16_rn(acc[p][0]), h1 = bf16_rn(acc[p][1]),
                             h2 = bf16_rn(acc[p][2]), h3 = bf16_rn(acc[p][3]);
        *(ushort4*)(oh + o) = make_ushort4(h0, h1, h2, h3);
        *(ushort4*)(ol + o) = make_ushort4(bf16_rn(acc[p][0] - bf16_f32(h0)),
                                           bf16_rn(acc[p][1] - bf16_f32(h1)),
                                           bf16_rn(acc[p][2] - bf16_f32(h2)),
                                           bf16_rn(acc[p][3] - bf16_f32(h3)));
    }
}

// ----------------------------------------------------------------------------
extern "C" void kernel_launch(void* const* d_in, const int* in_sizes, int n_in,
                              void* d_out, int out_size, void* d_ws, size_t ws_size,
                              hipStream_t stream)
{
    const float* x      = (const float*)d_in[0];
    const float* attn   = (const float*)d_in[1];
    const float* sims   = (const float*)d_in[2];
    const int*   sinds  = (const int*)d_in[3];
    const float* v_w    = (const float*)d_in[4];
    const float* v_b    = (const float*)d_in[5];
    const float* proj_w = (const float*)d_in[6];
    const float* proj_b = (const float*)d_in[7];
    float* out = (float*)d_out;

    char* ws = (char*)d_ws;
    float*          v   = (float*)ws;                                   // 268 MB
    unsigned short* xh  = (unsigned short*)(ws + 268435456);            // 134 MB
    unsigned short* xl  = (unsigned short*)(ws + 268435456 + 134217728);// 134 MB
    float*          wgt = (float*)(ws + 536870912);                     // 25.7 MB
    unsigned short* vwh = (unsigned short*)(ws + 536870912 + 25690112);
    unsigned short* vwl = vwh + 262144;
    unsigned short* pwh = vwl + 262144;
    unsigned short* pwl = pwh + 262144;
    unsigned short* aggh = xh;   // x dead after gemm1
    unsigned short* aggl = xl;

    split_kernel<<<2048, 256, 0, stream>>>(x, xh, xl, Mtot * 512 / 8);
    split_kernel<<<128, 256, 0, stream>>>(v_w, vwh, vwl, 262144 / 8);
    split_kernel<<<128, 256, 0, stream>>>(proj_w, pwh, pwl, 262144 / 8);

    gemm_c3<false><<<4096, 256, 0, stream>>>(xh, xl, vwh, vwl, v_b, v);
    wgt_kernel<<<512, 256, 0, stream>>>(sims, sinds, wgt);
    agg_kernel<<<16384, 128, 0, stream>>>(v, attn, wgt, aggh, aggl);
    gemm_c3<true><<<4096, 256, 0, stream>>>(aggh, aggl, pwh, pwl, proj_b, out);
}

// Round 9
// 2518.123 us; speedup vs baseline: 1.0245x; 1.0245x over previous
//
#include <hip/hip_runtime.h>

#define Hh   128
#define Ww   128
#define Cc   512
#define NHh  16
#define Kk   7
#define Ss   9
#define HW   (Hh*Ww)          // 16384
#define Mtot (8*HW)           // 131072
#define KK2  (Kk*Kk)          // 49

typedef __attribute__((ext_vector_type(8))) short bf16x8;
typedef __attribute__((ext_vector_type(4))) float f32x4;

#define AS1 __attribute__((address_space(1)))
#define AS3 __attribute__((address_space(3)))

__device__ __forceinline__ unsigned short bf16_rn(float f) {
    union { float f; unsigned u; } v; v.f = f;
    unsigned r = v.u + 0x7fffu + ((v.u >> 16) & 1u);
    return (unsigned short)(r >> 16);
}
__device__ __forceinline__ float bf16_f32(unsigned short h) {
    union { unsigned u; float f; } v; v.u = ((unsigned)h) << 16; return v.f;
}

// ----------------------------------------------------------------------------
// split f32 -> (hi, lo) bf16.  n8 = n/8  (unchanged)
// ----------------------------------------------------------------------------
__global__ __launch_bounds__(256) void split_kernel(const float* __restrict__ src,
                                                    unsigned short* __restrict__ dh,
                                                    unsigned short* __restrict__ dl,
                                                    int n8)
{
    for (int i = blockIdx.x * 256 + threadIdx.x; i < n8; i += gridDim.x * 256) {
        const float4* sp = (const float4*)src + (size_t)i * 2;
        const float4 a = sp[0], b = sp[1];
        const float vv[8] = {a.x, a.y, a.z, a.w, b.x, b.y, b.z, b.w};
        unsigned short h[8], l[8];
#pragma unroll
        for (int j = 0; j < 8; ++j) {
            h[j] = bf16_rn(vv[j]);
            l[j] = bf16_rn(vv[j] - bf16_f32(h[j]));
        }
        ushort4* dhp = (ushort4*)dh + (size_t)i * 2;
        ushort4* dlp = (ushort4*)dl + (size_t)i * 2;
        dhp[0] = make_ushort4(h[0], h[1], h[2], h[3]);
        dhp[1] = make_ushort4(h[4], h[5], h[6], h[7]);
        dlp[0] = make_ushort4(l[0], l[1], l[2], l[3]);
        dlp[1] = make_ushort4(l[4], l[5], l[6], l[7]);
    }
}

// ----------------------------------------------------------------------------
// Concat-K split GEMM (unchanged from round 6 — validated)
// ----------------------------------------------------------------------------
template<bool NT>
__global__ __launch_bounds__(256, 4) void gemm_c3(
        const unsigned short* __restrict__ Ah, const unsigned short* __restrict__ Al,
        const unsigned short* __restrict__ Wh, const unsigned short* __restrict__ Wl,
        const float* __restrict__ bias, float* __restrict__ C)
{
    __shared__ char lds[32768];             // 2 buffers x (A 8KB + B 8KB)
    const int tid  = threadIdx.x;
    const int lane = tid & 63;
    const int w    = tid >> 6;
    const int wr   = w >> 1, wc = w & 1;

    const int id = ((blockIdx.x & 7) << 9) + (blockIdx.x >> 3);
    const int m0 = (id >> 2) << 7;
    const int n0 = (id & 3) << 7;

    const size_t aRow = (size_t)(m0 + w * 16 + (lane >> 2)) * 1024 + ((lane & 3) << 4);
    const size_t bRow = (size_t)(n0 + w * 16 + (lane >> 2)) * 1024 + ((lane & 3) << 4);

    f32x4 acc[4][4];
#pragma unroll
    for (int a = 0; a < 4; ++a)
#pragma unroll
        for (int b = 0; b < 4; ++b) acc[a][b] = (f32x4)0.f;

    const int aoffL = (wr * 64 + (lane & 15)) * 64 + ((lane >> 4) << 4);
    const int boffL = 8192 + (wc * 64 + (lane & 15)) * 64 + ((lane >> 4) << 4);

#pragma unroll
    for (int q = 0; q < 2; ++q) {
        __builtin_amdgcn_global_load_lds(
            (const AS1 void*)((const char*)Ah + aRow + (size_t)q * 65536),
            (AS3 void*)(&lds[(q * 4 + w) * 1024]), 16, 0, 0);
        __builtin_amdgcn_global_load_lds(
            (const AS1 void*)((const char*)Wh + bRow + (size_t)q * 65536),
            (AS3 void*)(&lds[8192 + (q * 4 + w) * 1024]), 16, 0, 0);
    }
    __syncthreads();

    int tn = 1, kbn = 0;    // (t, kb) of the NEXT kt to stage
    for (int kt = 0; kt < 48; ++kt) {
        const int cur = kt & 1;
        if (kt < 47) {
            const char* Ap = (const char*)((tn < 2) ? Ah : Al) + (size_t)kbn * 64;
            const char* Bp = (const char*)((tn == 1) ? Wl : Wh) + (size_t)kbn * 64;
            char* dst = &lds[(cur ^ 1) * 16384];
#pragma unroll
            for (int q = 0; q < 2; ++q) {
                __builtin_amdgcn_global_load_lds(
                    (const AS1 void*)(Ap + aRow + (size_t)q * 65536),
                    (AS3 void*)(dst + (q * 4 + w) * 1024), 16, 0, 0);
                __builtin_amdgcn_global_load_lds(
                    (const AS1 void*)(Bp + bRow + (size_t)q * 65536),
                    (AS3 void*)(dst + 8192 + (q * 4 + w) * 1024), 16, 0, 0);
            }
            if (++tn == 3) { tn = 0; ++kbn; }
        }
        const char* LA = &lds[cur * 16384];
        bf16x8 a[4], b[4];
#pragma unroll
        for (int mi = 0; mi < 4; ++mi) a[mi] = *(const bf16x8*)(LA + aoffL + mi * 1024);
#pragma unroll
        for (int ni = 0; ni < 4; ++ni) b[ni] = *(const bf16x8*)(LA + boffL + ni * 1024);
#pragma unroll
        for (int mi = 0; mi < 4; ++mi)
#pragma unroll
            for (int ni = 0; ni < 4; ++ni)
                acc[mi][ni] = __builtin_amdgcn_mfma_f32_16x16x32_bf16(a[mi], b[ni], acc[mi][ni], 0, 0, 0);
        __syncthreads();
    }

    const int crow = (lane >> 4) << 2;
    const int ccol = lane & 15;
#pragma unroll
    for (int ni = 0; ni < 4; ++ni) {
        const int col = n0 + wc * 64 + ni * 16 + ccol;
        const float bv = bias[col];
#pragma unroll
        for (int mi = 0; mi < 4; ++mi) {
            float* cp = C + (size_t)(m0 + wr * 64 + mi * 16 + crow) * 512 + col;
#pragma unroll
            for (int r = 0; r < 4; ++r) {
                const float val = acc[mi][ni][r] + bv;
                if (NT) __builtin_nontemporal_store(val, cp + (size_t)r * 512);
                else    cp[(size_t)r * 512] = val;
            }
        }
    }
}

// ----------------------------------------------------------------------------
// wgt[pix][k] (unchanged)
// ----------------------------------------------------------------------------
__global__ __launch_bounds__(256) void wgt_kernel(const float* __restrict__ sims,
                                                  const int* __restrict__ sinds,
                                                  float* __restrict__ wgt)
{
    const int pix = blockIdx.x * 256 + threadIdx.x;
    const int b  = pix >> 14;
    const int ij = pix & 16383;
    const int i  = ij >> 7;
    const int j  = ij & 127;

    float os[Ss]; int oi[Ss];
    const float* sp = sims + (size_t)pix * Ss;
    const int*   ip = sinds + (size_t)pix * Ss;
#pragma unroll
    for (int s = 0; s < Ss; ++s) { os[s] = sp[s]; oi[s] = ip[s]; }

    const int si = min(max(i - 3, 0), Hh - Kk);
    const int sj = min(max(j - 3, 0), Ww - Kk);
    float* wp = wgt + (size_t)pix * KK2;

    int kidx = 0;
    for (int ki = 0; ki < Kk; ++ki) {
        const int ni = si + ki;
        for (int kj = 0; kj < Kk; ++kj, ++kidx) {
            const int nj = sj + kj;
            const int npix = (b << 14) + (ni << 7) + nj;
            const float* nsp = sims + (size_t)npix * Ss;
            const int*   nip = sinds + (size_t)npix * Ss;
            float acc = 0.f;
#pragma unroll
            for (int t = 0; t < Ss; ++t) {
                const int   nid = nip[t];
                const float nsm = nsp[t];
                float m = 0.f;
#pragma unroll
                for (int s = 0; s < Ss; ++s) m += (oi[s] == nid) ? os[s] : 0.f;
                acc += m * nsm;
            }
            wp[kidx] = acc;
        }
    }
}

// ----------------------------------------------------------------------------
// aggregation, 8-pixel row tiles, explicit register double-buffer expressed
// ENTIRELY via macros on kernel-scope arrays (no function params -> SROA
// must promote; round 8's helper-param version spilled to scratch).
// amdgpu_waves_per_eu(3,3) pins allocator at 3 waves/EU (VGPR cap ~170) so
// it cannot clamp to 84-and-spill. coef back to f32 [8][16][51] (25.5 KB,
// 6 blocks/CU).
// ----------------------------------------------------------------------------
#define LOADR(VR, KI) { const float* _rp = r0 + (size_t)(KI) * 65536;           \
    _Pragma("unroll") for (int c = 0; c < 14; ++c)                              \
        VR[c] = *(const float4*)(_rp + c * Cc); }

#define FMAR(VR, KI, VARC) {                                                    \
    _Pragma("unroll") for (int p = 0; p < 8; ++p) {                             \
        const int d = ((VARC) == 0) ? 0                                         \
                    : ((VARC) == 1) ? -((p < 3) ? p : 3)                        \
                                    : (3 - ((p > 4) ? (p - 4) : 0));            \
        _Pragma("unroll") for (int kj = 0; kj < 7; ++kj) {                      \
            const float  cf = cbp[p * 816 + (KI) * 7 + kj];                     \
            const float4 vv = VR[p + kj + d];                                   \
            acc[p][0] += cf * vv.x; acc[p][1] += cf * vv.y;                     \
            acc[p][2] += cf * vv.z; acc[p][3] += cf * vv.w; } } }

#define AGG_PIPE(VARC) {                                                        \
    LOADR(vrA, 0) LOADR(vrB, 1)                                                 \
    FMAR(vrA, 0, VARC) LOADR(vrA, 2)                                            \
    FMAR(vrB, 1, VARC) LOADR(vrB, 3)                                            \
    FMAR(vrA, 2, VARC) LOADR(vrA, 4)                                            \
    FMAR(vrB, 3, VARC) LOADR(vrB, 5)                                            \
    FMAR(vrA, 4, VARC) LOADR(vrA, 6)                                            \
    FMAR(vrB, 5, VARC)                                                          \
    FMAR(vrA, 6, VARC) }

__global__ __launch_bounds__(128)
__attribute__((amdgpu_waves_per_eu(3, 3)))
void agg_kernel(const float* __restrict__ v,
                const float* __restrict__ attn,
                const float* __restrict__ wgt,
                unsigned short* __restrict__ oh,
                unsigned short* __restrict__ ol)
{
    const int t   = ((blockIdx.x & 7) << 11) | (blockIdx.x >> 3);
    const int b   = t >> 11;
    const int rem = t & 2047;
    const int i   = rem >> 4;
    const int j0  = (rem & 15) << 3;
    const int tid = threadIdx.x;
    const int nh  = tid >> 3;

    __shared__ float coef[8 * 16 * 51];    // 25.5 KB

    const int pixbase = (b << 14) | (i << 7) | j0;
    for (int e = tid; e < 8 * 16 * KK2; e += 128) {
        const int p = e / (16 * KK2);
        const int r = e - p * (16 * KK2);
        const int h = r / KK2;
        const int k = r - h * KK2;
        coef[(p * 16 + h) * 51 + k] =
            attn[((size_t)(b * NHh + h) * HW + (size_t)((i << 7) | (j0 + p))) * KK2 + k]
            * wgt[(size_t)(pixbase + p) * KK2 + k];
    }

    f32x4 acc[8];
#pragma unroll
    for (int p = 0; p < 8; ++p) acc[p] = (f32x4)0.f;

    const int si = min(max(i - 3, 0), Hh - Kk);
    const int cb = (j0 == 0) ? 0 : ((j0 == 120) ? (Ww - 14) : (j0 - 3));
    const float* r0 = v + ((size_t)b << 23) + (size_t)si * 65536 + ((size_t)cb << 9) + (tid << 2);
    const float* cbp;

    __syncthreads();
    cbp = coef + nh * 51;

    float4 vrA[14], vrB[14];
    if (j0 == 0)          AGG_PIPE(1)
    else if (j0 == 120)   AGG_PIPE(2)
    else                  AGG_PIPE(0)

#pragma unroll
    for (int p = 0; p < 8; ++p) {
        const size_t o = (size_t)(pixbase + p) * Cc + (size_t)(tid << 2);
        const unsigned short h0 = bf16_rn(acc[p][0]), h1 = bf16_rn(acc[p][1]),
                             h2 = bf16_rn(acc[p][2]), h3 = bf16_rn(acc[p][3]);
        *(ushort4*)(oh + o) = make_ushort4(h0, h1, h2, h3);
        *(ushort4*)(ol + o) = make_ushort4(bf16_rn(acc[p][0] - bf16_f32(h0)),
                                           bf16_rn(acc[p][1] - bf16_f32(h1)),
                                           bf16_rn(acc[p][2] - bf16_f32(h2)),
                                           bf16_rn(acc[p][3] - bf16_f32(h3)));
    }
}

// ----------------------------------------------------------------------------
extern "C" void kernel_launch(void* const* d_in, const int* in_sizes, int n_in,
                              void* d_out, int out_size, void* d_ws, size_t ws_size,
                              hipStream_t stream)
{
    const float* x      = (const float*)d_in[0];
    const float* attn   = (const float*)d_in[1];
    const float* sims   = (const float*)d_in[2];
    const int*   sinds  = (const int*)d_in[3];
    const float* v_w    = (const float*)d_in[4];
    const float* v_b    = (const float*)d_in[5];
    const float* proj_w = (const float*)d_in[6];
    const float* proj_b = (const float*)d_in[7];
    float* out = (float*)d_out;

    char* ws = (char*)d_ws;
    float*          v   = (float*)ws;                                   // 268 MB
    unsigned short* xh  = (unsigned short*)(ws + 268435456);            // 134 MB
    unsigned short* xl  = (unsigned short*)(ws + 268435456 + 134217728);// 134 MB
    float*          wgt = (float*)(ws + 536870912);                     // 25.7 MB
    unsigned short* vwh = (unsigned short*)(ws + 536870912 + 25690112);
    unsigned short* vwl = vwh + 262144;
    unsigned short* pwh = vwl + 262144;
    unsigned short* pwl = pwh + 262144;
    unsigned short* aggh = xh;   // x dead after gemm1
    unsigned short* aggl = xl;

    split_kernel<<<2048, 256, 0, stream>>>(x, xh, xl, Mtot * 512 / 8);
    split_kernel<<<128, 256, 0, stream>>>(v_w, vwh, vwl, 262144 / 8);
    split_kernel<<<128, 256, 0, stream>>>(proj_w, pwh, pwl, 262144 / 8);

    gemm_c3<false><<<4096, 256, 0, stream>>>(xh, xl, vwh, vwl, v_b, v);
    wgt_kernel<<<512, 256, 0, stream>>>(sims, sinds, wgt);
    agg_kernel<<<16384, 128, 0, stream>>>(v, attn, wgt, aggh, aggl);
    gemm_c3<true><<<4096, 256, 0, stream>>>(aggh, aggl, pwh, pwl, proj_b, out);
}

// Round 10
// 1241.093 us; speedup vs baseline: 2.0787x; 2.0290x over previous
//
#include <hip/hip_runtime.h>

#define Hh   128
#define Ww   128
#define Cc   512
#define NHh  16
#define Kk   7
#define Ss   9
#define HW   (Hh*Ww)          // 16384
#define Mtot (8*HW)           // 131072
#define KK2  (Kk*Kk)          // 49

typedef __attribute__((ext_vector_type(8))) short bf16x8;
typedef __attribute__((ext_vector_type(4))) float f32x4;
typedef __attribute__((ext_vector_type(2))) float f32x2;

#define AS1 __attribute__((address_space(1)))
#define AS3 __attribute__((address_space(3)))

__device__ __forceinline__ unsigned short bf16_rn(float f) {
    union { float f; unsigned u; } v; v.f = f;
    unsigned r = v.u + 0x7fffu + ((v.u >> 16) & 1u);
    return (unsigned short)(r >> 16);
}
__device__ __forceinline__ float bf16_f32(unsigned short h) {
    union { unsigned u; float f; } v; v.u = ((unsigned)h) << 16; return v.f;
}

// ----------------------------------------------------------------------------
// split f32 -> (hi, lo) bf16.  n8 = n/8  (unchanged)
// ----------------------------------------------------------------------------
__global__ __launch_bounds__(256) void split_kernel(const float* __restrict__ src,
                                                    unsigned short* __restrict__ dh,
                                                    unsigned short* __restrict__ dl,
                                                    int n8)
{
    for (int i = blockIdx.x * 256 + threadIdx.x; i < n8; i += gridDim.x * 256) {
        const float4* sp = (const float4*)src + (size_t)i * 2;
        const float4 a = sp[0], b = sp[1];
        const float vv[8] = {a.x, a.y, a.z, a.w, b.x, b.y, b.z, b.w};
        unsigned short h[8], l[8];
#pragma unroll
        for (int j = 0; j < 8; ++j) {
            h[j] = bf16_rn(vv[j]);
            l[j] = bf16_rn(vv[j] - bf16_f32(h[j]));
        }
        ushort4* dhp = (ushort4*)dh + (size_t)i * 2;
        ushort4* dlp = (ushort4*)dl + (size_t)i * 2;
        dhp[0] = make_ushort4(h[0], h[1], h[2], h[3]);
        dhp[1] = make_ushort4(h[4], h[5], h[6], h[7]);
        dlp[0] = make_ushort4(l[0], l[1], l[2], l[3]);
        dlp[1] = make_ushort4(l[4], l[5], l[6], l[7]);
    }
}

// ----------------------------------------------------------------------------
// Concat-K split GEMM (unchanged from round 6 — validated)
// ----------------------------------------------------------------------------
template<bool NT>
__global__ __launch_bounds__(256, 4) void gemm_c3(
        const unsigned short* __restrict__ Ah, const unsigned short* __restrict__ Al,
        const unsigned short* __restrict__ Wh, const unsigned short* __restrict__ Wl,
        const float* __restrict__ bias, float* __restrict__ C)
{
    __shared__ char lds[32768];             // 2 buffers x (A 8KB + B 8KB)
    const int tid  = threadIdx.x;
    const int lane = tid & 63;
    const int w    = tid >> 6;
    const int wr   = w >> 1, wc = w & 1;

    const int id = ((blockIdx.x & 7) << 9) + (blockIdx.x >> 3);
    const int m0 = (id >> 2) << 7;
    const int n0 = (id & 3) << 7;

    const size_t aRow = (size_t)(m0 + w * 16 + (lane >> 2)) * 1024 + ((lane & 3) << 4);
    const size_t bRow = (size_t)(n0 + w * 16 + (lane >> 2)) * 1024 + ((lane & 3) << 4);

    f32x4 acc[4][4];
#pragma unroll
    for (int a = 0; a < 4; ++a)
#pragma unroll
        for (int b = 0; b < 4; ++b) acc[a][b] = (f32x4)0.f;

    const int aoffL = (wr * 64 + (lane & 15)) * 64 + ((lane >> 4) << 4);
    const int boffL = 8192 + (wc * 64 + (lane & 15)) * 64 + ((lane >> 4) << 4);

#pragma unroll
    for (int q = 0; q < 2; ++q) {
        __builtin_amdgcn_global_load_lds(
            (const AS1 void*)((const char*)Ah + aRow + (size_t)q * 65536),
            (AS3 void*)(&lds[(q * 4 + w) * 1024]), 16, 0, 0);
        __builtin_amdgcn_global_load_lds(
            (const AS1 void*)((const char*)Wh + bRow + (size_t)q * 65536),
            (AS3 void*)(&lds[8192 + (q * 4 + w) * 1024]), 16, 0, 0);
    }
    __syncthreads();

    int tn = 1, kbn = 0;    // (t, kb) of the NEXT kt to stage
    for (int kt = 0; kt < 48; ++kt) {
        const int cur = kt & 1;
        if (kt < 47) {
            const char* Ap = (const char*)((tn < 2) ? Ah : Al) + (size_t)kbn * 64;
            const char* Bp = (const char*)((tn == 1) ? Wl : Wh) + (size_t)kbn * 64;
            char* dst = &lds[(cur ^ 1) * 16384];
#pragma unroll
            for (int q = 0; q < 2; ++q) {
                __builtin_amdgcn_global_load_lds(
                    (const AS1 void*)(Ap + aRow + (size_t)q * 65536),
                    (AS3 void*)(dst + (q * 4 + w) * 1024), 16, 0, 0);
                __builtin_amdgcn_global_load_lds(
                    (const AS1 void*)(Bp + bRow + (size_t)q * 65536),
                    (AS3 void*)(dst + 8192 + (q * 4 + w) * 1024), 16, 0, 0);
            }
            if (++tn == 3) { tn = 0; ++kbn; }
        }
        const char* LA = &lds[cur * 16384];
        bf16x8 a[4], b[4];
#pragma unroll
        for (int mi = 0; mi < 4; ++mi) a[mi] = *(const bf16x8*)(LA + aoffL + mi * 1024);
#pragma unroll
        for (int ni = 0; ni < 4; ++ni) b[ni] = *(const bf16x8*)(LA + boffL + ni * 1024);
#pragma unroll
        for (int mi = 0; mi < 4; ++mi)
#pragma unroll
            for (int ni = 0; ni < 4; ++ni)
                acc[mi][ni] = __builtin_amdgcn_mfma_f32_16x16x32_bf16(a[mi], b[ni], acc[mi][ni], 0, 0, 0);
        __syncthreads();
    }

    const int crow = (lane >> 4) << 2;
    const int ccol = lane & 15;
#pragma unroll
    for (int ni = 0; ni < 4; ++ni) {
        const int col = n0 + wc * 64 + ni * 16 + ccol;
        const float bv = bias[col];
#pragma unroll
        for (int mi = 0; mi < 4; ++mi) {
            float* cp = C + (size_t)(m0 + wr * 64 + mi * 16 + crow) * 512 + col;
#pragma unroll
            for (int r = 0; r < 4; ++r) {
                const float val = acc[mi][ni][r] + bv;
                if (NT) __builtin_nontemporal_store(val, cp + (size_t)r * 512);
                else    cp[(size_t)r * 512] = val;
            }
        }
    }
}

// ----------------------------------------------------------------------------
// wgt[pix][k] (unchanged)
// ----------------------------------------------------------------------------
__global__ __launch_bounds__(256) void wgt_kernel(const float* __restrict__ sims,
                                                  const int* __restrict__ sinds,
                                                  float* __restrict__ wgt)
{
    const int pix = blockIdx.x * 256 + threadIdx.x;
    const int b  = pix >> 14;
    const int ij = pix & 16383;
    const int i  = ij >> 7;
    const int j  = ij & 127;

    float os[Ss]; int oi[Ss];
    const float* sp = sims + (size_t)pix * Ss;
    const int*   ip = sinds + (size_t)pix * Ss;
#pragma unroll
    for (int s = 0; s < Ss; ++s) { os[s] = sp[s]; oi[s] = ip[s]; }

    const int si = min(max(i - 3, 0), Hh - Kk);
    const int sj = min(max(j - 3, 0), Ww - Kk);
    float* wp = wgt + (size_t)pix * KK2;

    int kidx = 0;
    for (int ki = 0; ki < Kk; ++ki) {
        const int ni = si + ki;
        for (int kj = 0; kj < Kk; ++kj, ++kidx) {
            const int nj = sj + kj;
            const int npix = (b << 14) + (ni << 7) + nj;
            const float* nsp = sims + (size_t)npix * Ss;
            const int*   nip = sinds + (size_t)npix * Ss;
            float acc = 0.f;
#pragma unroll
            for (int t = 0; t < Ss; ++t) {
                const int   nid = nip[t];
                const float nsm = nsp[t];
                float m = 0.f;
#pragma unroll
                for (int s = 0; s < Ss; ++s) m += (oi[s] == nid) ? os[s] : 0.f;
                acc += m * nsm;
            }
            wp[kidx] = acc;
        }
    }
}

// ----------------------------------------------------------------------------
// aggregation v2: 8-pixel row tiles, 256 threads/block, 2 channels/thread
// (f32x2). Register double-buffer now FITS a low budget: vrA+vrB = 56 VGPR,
// acc = 16, misc ~25 -> ~100 total. NO occupancy hints (they pinned the
// allocator at 84 and forced scratch in rounds 4/8/9). LDS coef f32 25.5KB
// -> 6 blocks/CU; VGPR ~100 -> ~5 waves/EU -> occupancy ~60% AND pipelined.
// Numerics identical to round 4 (f32 coef, f32 v, same sum order).
// ----------------------------------------------------------------------------
#define LOADR(VR, KI) { const float* _rp = r0 + (size_t)(KI) * 65536;           \
    _Pragma("unroll") for (int c = 0; c < 14; ++c)                              \
        VR[c] = *(const f32x2*)(_rp + c * Cc); }

#define FMAR(VR, KI, VARC) {                                                    \
    _Pragma("unroll") for (int p = 0; p < 8; ++p) {                             \
        const int d = ((VARC) == 0) ? 0                                         \
                    : ((VARC) == 1) ? -((p < 3) ? p : 3)                        \
                                    : (3 - ((p > 4) ? (p - 4) : 0));            \
        _Pragma("unroll") for (int kj = 0; kj < 7; ++kj) {                      \
            const float cf = cbp[p * 816 + (KI) * 7 + kj];                      \
            const f32x2 vv = VR[p + kj + d];                                    \
            acc[p][0] += cf * vv[0]; acc[p][1] += cf * vv[1]; } } }

#define AGG_PIPE(VARC) {                                                        \
    LOADR(vrA, 0) LOADR(vrB, 1)                                                 \
    FMAR(vrA, 0, VARC) LOADR(vrA, 2)                                            \
    FMAR(vrB, 1, VARC) LOADR(vrB, 3)                                            \
    FMAR(vrA, 2, VARC) LOADR(vrA, 4)                                            \
    FMAR(vrB, 3, VARC) LOADR(vrB, 5)                                            \
    FMAR(vrA, 4, VARC) LOADR(vrA, 6)                                            \
    FMAR(vrB, 5, VARC)                                                          \
    FMAR(vrA, 6, VARC) }

__global__ __launch_bounds__(256)
void agg_kernel(const float* __restrict__ v,
                const float* __restrict__ attn,
                const float* __restrict__ wgt,
                unsigned short* __restrict__ oh,
                unsigned short* __restrict__ ol)
{
    // 16384 blocks; XCD x owns image x, row-major sweep within image
    const int t   = ((blockIdx.x & 7) << 11) | (blockIdx.x >> 3);
    const int b   = t >> 11;
    const int rem = t & 2047;
    const int i   = rem >> 4;
    const int j0  = (rem & 15) << 3;
    const int tid = threadIdx.x;         // 0..255, channel pair = 2*tid
    const int nh  = tid >> 4;            // 16 threads per head (32 ch)

    __shared__ float coef[8 * 16 * 51];  // 25.5 KB

    const int pixbase = (b << 14) | (i << 7) | j0;
    for (int e = tid; e < 8 * 16 * KK2; e += 256) {
        const int p = e / (16 * KK2);
        const int r = e - p * (16 * KK2);
        const int h = r / KK2;
        const int k = r - h * KK2;
        coef[(p * 16 + h) * 51 + k] =
            attn[((size_t)(b * NHh + h) * HW + (size_t)((i << 7) | (j0 + p))) * KK2 + k]
            * wgt[(size_t)(pixbase + p) * KK2 + k];
    }

    f32x2 acc[8];
#pragma unroll
    for (int p = 0; p < 8; ++p) acc[p] = (f32x2)0.f;

    const int si = min(max(i - 3, 0), Hh - Kk);
    const int cb = (j0 == 0) ? 0 : ((j0 == 120) ? (Ww - 14) : (j0 - 3));
    const float* r0 = v + ((size_t)b << 23) + (size_t)si * 65536 + ((size_t)cb << 9) + (tid << 1);
    const float* cbp;

    __syncthreads();
    cbp = coef + nh * 51;

    f32x2 vrA[14], vrB[14];
    if (j0 == 0)          AGG_PIPE(1)
    else if (j0 == 120)   AGG_PIPE(2)
    else                  AGG_PIPE(0)

#pragma unroll
    for (int p = 0; p < 8; ++p) {
        const size_t o = (size_t)(pixbase + p) * Cc + (tid << 1);
        const unsigned short h0 = bf16_rn(acc[p][0]), h1 = bf16_rn(acc[p][1]);
        *(ushort2*)(oh + o) = make_ushort2(h0, h1);
        *(ushort2*)(ol + o) = make_ushort2(bf16_rn(acc[p][0] - bf16_f32(h0)),
                                           bf16_rn(acc[p][1] - bf16_f32(h1)));
    }
}

// ----------------------------------------------------------------------------
extern "C" void kernel_launch(void* const* d_in, const int* in_sizes, int n_in,
                              void* d_out, int out_size, void* d_ws, size_t ws_size,
                              hipStream_t stream)
{
    const float* x      = (const float*)d_in[0];
    const float* attn   = (const float*)d_in[1];
    const float* sims   = (const float*)d_in[2];
    const int*   sinds  = (const int*)d_in[3];
    const float* v_w    = (const float*)d_in[4];
    const float* v_b    = (const float*)d_in[5];
    const float* proj_w = (const float*)d_in[6];
    const float* proj_b = (const float*)d_in[7];
    float* out = (float*)d_out;

    char* ws = (char*)d_ws;
    float*          v   = (float*)ws;                                   // 268 MB
    unsigned short* xh  = (unsigned short*)(ws + 268435456);            // 134 MB
    unsigned short* xl  = (unsigned short*)(ws + 268435456 + 134217728);// 134 MB
    float*          wgt = (float*)(ws + 536870912);                     // 25.7 MB
    unsigned short* vwh = (unsigned short*)(ws + 536870912 + 25690112);
    unsigned short* vwl = vwh + 262144;
    unsigned short* pwh = vwl + 262144;
    unsigned short* pwl = pwh + 262144;
    unsigned short* aggh = xh;   // x dead after gemm1
    unsigned short* aggl = xl;

    split_kernel<<<2048, 256, 0, stream>>>(x, xh, xl, Mtot * 512 / 8);
    split_kernel<<<128, 256, 0, stream>>>(v_w, vwh, vwl, 262144 / 8);
    split_kernel<<<128, 256, 0, stream>>>(proj_w, pwh, pwl, 262144 / 8);

    gemm_c3<false><<<4096, 256, 0, stream>>>(xh, xl, vwh, vwl, v_b, v);
    wgt_kernel<<<512, 256, 0, stream>>>(sims, sinds, wgt);
    agg_kernel<<<16384, 256, 0, stream>>>(v, attn, wgt, aggh, aggl);
    gemm_c3<true><<<4096, 256, 0, stream>>>(aggh, aggl, pwh, pwl, proj_b, out);
}